// Round 2
// baseline (101.423 us; speedup 1.0000x reference)
//
#include <hip/hip_runtime.h>

// SurveyEmbeddings forward:
//   placeholder = (answer<=1) ? answer*lin_w + lin_b : ans_emb[answer]
//   out = LN(placeholder)*ln_g + ln_b + alpha*year_emb[year[b]] + beta*q_emb[q]
//
// out[B=4096, Q=1024, D=16] fp32 (268 MB) — memory-bound, write-dominated.
// Strategy: 4 lanes per row, 1 float4 per lane (perfect 16B/lane coalescing
// on both the ans_emb gather and the output store). LN over D=16 via two
// shfl_xor steps in the 4-lane group. 2x unroll for MLP; int32 indexing.

typedef float f32x4 __attribute__((ext_vector_type(4)));

#define LN_EPS 1e-5f

template <bool QPOW2>
__global__ __launch_bounds__(256) void survey_fwd(
    const int* __restrict__ year,
    const int* __restrict__ answer,
    const f32x4* __restrict__ ans_emb,   // [VOCAB][4]
    const f32x4* __restrict__ lin_w,     // [4]
    const f32x4* __restrict__ lin_b,     // [4]
    const f32x4* __restrict__ ln_g,      // [4]
    const f32x4* __restrict__ ln_b,      // [4]
    const f32x4* __restrict__ year_emb,  // [N_YEARS][4]
    const f32x4* __restrict__ q_emb,     // [Q][4]
    const float* __restrict__ alpha,
    const float* __restrict__ beta,
    f32x4* __restrict__ out,             // [B*Q][4]
    int nrows, int Q, int qShift)
{
    const float A  = alpha[0];
    const float Bc = beta[0];

    const int sub = threadIdx.x & 3;     // float4 slot within the D=16 row
    const f32x4 w  = lin_w[sub];
    const f32x4 lb = lin_b[sub];
    const f32x4 g  = ln_g[sub];
    const f32x4 bb = ln_b[sub];

    const int total  = nrows * 4;        // 16.8M max — fits int32
    const int stride = (int)(gridDim.x * blockDim.x);
    int i = (int)(blockIdx.x * blockDim.x + threadIdx.x);

    // 2x unrolled main loop: two independent answer->gather chains in flight.
    for (; i + stride < total; i += 2 * stride) {
        const int i0 = i, i1 = i + stride;
        const int row0 = i0 >> 2, row1 = i1 >> 2;

        // issue all independent loads first
        const int a0 = __builtin_nontemporal_load(&answer[row0]);
        const int a1 = __builtin_nontemporal_load(&answer[row1]);

        const int b0 = QPOW2 ? (row0 >> qShift) : (row0 / Q);
        const int b1 = QPOW2 ? (row1 >> qShift) : (row1 / Q);
        const int q0 = QPOW2 ? (row0 & (Q - 1)) : (row0 - b0 * Q);
        const int q1 = QPOW2 ? (row1 & (Q - 1)) : (row1 - b1 * Q);

        const int yr0 = year[b0];
        const int yr1 = year[b1];

        f32x4 v0 = ans_emb[a0 * 4 + sub];
        f32x4 v1 = ans_emb[a1 * 4 + sub];
        const f32x4 qe0 = q_emb[q0 * 4 + sub];
        const f32x4 qe1 = q_emb[q1 * 4 + sub];
        const f32x4 ye0 = year_emb[yr0 * 4 + sub];
        const f32x4 ye1 = year_emb[yr1 * 4 + sub];

        // continuous-branch select (rare: a<=1 is ~0.05% of elements)
        if (a0 <= 1) {
            const float af = (float)a0;
            v0.x = af * w.x + lb.x; v0.y = af * w.y + lb.y;
            v0.z = af * w.z + lb.z; v0.w = af * w.w + lb.w;
        }
        if (a1 <= 1) {
            const float af = (float)a1;
            v1.x = af * w.x + lb.x; v1.y = af * w.y + lb.y;
            v1.z = af * w.z + lb.z; v1.w = af * w.w + lb.w;
        }

        // LayerNorm over D=16 across the 4-lane group (both rows interleaved)
        float s0 = v0.x + v0.y + v0.z + v0.w;
        float s1 = v1.x + v1.y + v1.z + v1.w;
        s0 += __shfl_xor(s0, 1); s1 += __shfl_xor(s1, 1);
        s0 += __shfl_xor(s0, 2); s1 += __shfl_xor(s1, 2);
        const float mu0 = s0 * 0.0625f, mu1 = s1 * 0.0625f;

        const float d0x = v0.x - mu0, d0y = v0.y - mu0, d0z = v0.z - mu0, d0w = v0.w - mu0;
        const float d1x = v1.x - mu1, d1y = v1.y - mu1, d1z = v1.z - mu1, d1w = v1.w - mu1;
        float ss0 = d0x * d0x + d0y * d0y + d0z * d0z + d0w * d0w;
        float ss1 = d1x * d1x + d1y * d1y + d1z * d1z + d1w * d1w;
        ss0 += __shfl_xor(ss0, 1); ss1 += __shfl_xor(ss1, 1);
        ss0 += __shfl_xor(ss0, 2); ss1 += __shfl_xor(ss1, 2);
        const float r0 = rsqrtf(ss0 * 0.0625f + LN_EPS);
        const float r1 = rsqrtf(ss1 * 0.0625f + LN_EPS);

        f32x4 o0, o1;
        o0.x = d0x * r0 * g.x + bb.x + A * ye0.x + Bc * qe0.x;
        o0.y = d0y * r0 * g.y + bb.y + A * ye0.y + Bc * qe0.y;
        o0.z = d0z * r0 * g.z + bb.z + A * ye0.z + Bc * qe0.z;
        o0.w = d0w * r0 * g.w + bb.w + A * ye0.w + Bc * qe0.w;
        o1.x = d1x * r1 * g.x + bb.x + A * ye1.x + Bc * qe1.x;
        o1.y = d1y * r1 * g.y + bb.y + A * ye1.y + Bc * qe1.y;
        o1.z = d1z * r1 * g.z + bb.z + A * ye1.z + Bc * qe1.z;
        o1.w = d1w * r1 * g.w + bb.w + A * ye1.w + Bc * qe1.w;

        __builtin_nontemporal_store(o0, &out[i0]);
        __builtin_nontemporal_store(o1, &out[i1]);
    }

    // remainder (at most one strided element)
    for (; i < total; i += stride) {
        const int row = i >> 2;
        const int a = __builtin_nontemporal_load(&answer[row]);
        f32x4 v = ans_emb[a * 4 + sub];
        if (a <= 1) {
            const float af = (float)a;
            v.x = af * w.x + lb.x; v.y = af * w.y + lb.y;
            v.z = af * w.z + lb.z; v.w = af * w.w + lb.w;
        }
        float s = v.x + v.y + v.z + v.w;
        s += __shfl_xor(s, 1);
        s += __shfl_xor(s, 2);
        const float mu = s * 0.0625f;
        const float dx = v.x - mu, dy = v.y - mu, dz = v.z - mu, dw = v.w - mu;
        float ss = dx * dx + dy * dy + dz * dz + dw * dw;
        ss += __shfl_xor(ss, 1);
        ss += __shfl_xor(ss, 2);
        const float r = rsqrtf(ss * 0.0625f + LN_EPS);

        const int b = QPOW2 ? (row >> qShift) : (row / Q);
        const int q = QPOW2 ? (row & (Q - 1)) : (row - b * Q);
        const int yr = year[b];
        const f32x4 ye = year_emb[yr * 4 + sub];
        const f32x4 qe = q_emb[q * 4 + sub];

        f32x4 o;
        o.x = dx * r * g.x + bb.x + A * ye.x + Bc * qe.x;
        o.y = dy * r * g.y + bb.y + A * ye.y + Bc * qe.y;
        o.z = dz * r * g.z + bb.z + A * ye.z + Bc * qe.z;
        o.w = dw * r * g.w + bb.w + A * ye.w + Bc * qe.w;
        __builtin_nontemporal_store(o, &out[i]);
    }
}

extern "C" void kernel_launch(void* const* d_in, const int* in_sizes, int n_in,
                              void* d_out, int out_size, void* d_ws, size_t ws_size,
                              hipStream_t stream) {
    const int*   year     = (const int*)d_in[0];
    const int*   answer   = (const int*)d_in[1];
    const f32x4* ans_emb  = (const f32x4*)d_in[2];
    const f32x4* lin_w    = (const f32x4*)d_in[3];
    const f32x4* lin_b    = (const f32x4*)d_in[4];
    const f32x4* ln_g     = (const f32x4*)d_in[5];
    const f32x4* ln_b     = (const f32x4*)d_in[6];
    const f32x4* year_emb = (const f32x4*)d_in[7];
    const f32x4* q_emb    = (const f32x4*)d_in[8];
    const float* alpha    = (const float*)d_in[9];
    const float* beta     = (const float*)d_in[10];
    float*       out      = (float*)d_out;

    const int B     = in_sizes[0];
    const int nrows = in_sizes[1];       // B*Q
    const int Q     = nrows / B;

    const long long total_threads = (long long)nrows * 4;
    int blocks = (int)((total_threads + 255) / 256);
    if (blocks > 8192) blocks = 8192;    // grid-stride: 8 iters/thread at full size

    const bool pow2 = (Q & (Q - 1)) == 0;
    int qShift = 0;
    while ((1 << qShift) < Q) ++qShift;

    if (pow2) {
        survey_fwd<true><<<blocks, 256, 0, stream>>>(
            year, answer, ans_emb, lin_w, lin_b, ln_g, ln_b, year_emb, q_emb,
            alpha, beta, (f32x4*)out, nrows, Q, qShift);
    } else {
        survey_fwd<false><<<blocks, 256, 0, stream>>>(
            year, answer, ans_emb, lin_w, lin_b, ln_g, ln_b, year_emb, q_emb,
            alpha, beta, (f32x4*)out, nrows, Q, qShift);
    }
}

// Round 3
// 57.848 us; speedup vs baseline: 1.7533x; 1.7533x over previous
//
#include <hip/hip_runtime.h>

// SurveyEmbeddings forward:
//   placeholder = (answer<=1) ? answer*lin_w + lin_b : ans_emb[answer]
//   out = LN(placeholder)*ln_g + ln_b + alpha*year_emb[year[b]] + beta*q_emb[q]
//
// out[B=4096, Q=1024, D=16] fp32 (268 MB) — memory-bound, write-dominated.
//
// R2 post-mortem: 2x unroll blew VGPR budget -> occupancy halved -> 2x slower.
// This kernel is TLP-latency-hidden, not ILP. So: one float4 per thread,
// no loop, __launch_bounds__(256,8) to pin 8 waves/SIMD (VGPR<=64).

typedef float f32x4 __attribute__((ext_vector_type(4)));

#define LN_EPS 1e-5f

template <bool QPOW2>
__global__ __launch_bounds__(256, 8) void survey_fwd(
    const int* __restrict__ year,
    const int* __restrict__ answer,
    const f32x4* __restrict__ ans_emb,   // [VOCAB][4]
    const f32x4* __restrict__ lin_w,     // [4]
    const f32x4* __restrict__ lin_b,     // [4]
    const f32x4* __restrict__ ln_g,      // [4]
    const f32x4* __restrict__ ln_b,      // [4]
    const f32x4* __restrict__ year_emb,  // [N_YEARS][4]
    const f32x4* __restrict__ q_emb,     // [Q][4]
    const float* __restrict__ alpha,
    const float* __restrict__ beta,
    f32x4* __restrict__ out,             // [B*Q][4]
    int total, int Q, int qShift)
{
    const int i = (int)(blockIdx.x * blockDim.x + threadIdx.x);
    if (i >= total) return;

    const int sub = threadIdx.x & 3;     // float4 slot within the D=16 row
    const int row = i >> 2;

    // answer: 4 lanes broadcast-read the same address (L1-served)
    const int a = answer[row];

    // categorical branch: gather 16B of the 64B embedding row (L1/L2-hot table)
    f32x4 v = ans_emb[a * 4 + sub];

    // continuous branch — rare (a<=1 is ~0.05% of elements); keep its table
    // loads inside the branch so lin_w/lin_b don't occupy hot-path VGPRs.
    if (a <= 1) {
        const f32x4 w  = lin_w[sub];
        const f32x4 lb = lin_b[sub];
        const float af = (float)a;
        v.x = af * w.x + lb.x;
        v.y = af * w.y + lb.y;
        v.z = af * w.z + lb.z;
        v.w = af * w.w + lb.w;
    }

    // LayerNorm over D=16 across the 4-lane group
    float s = v.x + v.y + v.z + v.w;
    s += __shfl_xor(s, 1);
    s += __shfl_xor(s, 2);
    const float mu = s * 0.0625f;

    const float dx = v.x - mu, dy = v.y - mu, dz = v.z - mu, dw = v.w - mu;
    float ss = dx * dx + dy * dy + dz * dz + dw * dw;
    ss += __shfl_xor(ss, 1);
    ss += __shfl_xor(ss, 2);
    const float r = rsqrtf(ss * 0.0625f + LN_EPS);

    const int b = QPOW2 ? (row >> qShift) : (row / Q);
    const int q = QPOW2 ? (row & (Q - 1)) : (row - b * Q);

    const int   yr = year[b];              // wave-uniform in practice (L1 hit)
    const f32x4 ye = year_emb[yr * 4 + sub];
    const f32x4 qe = q_emb[q * 4 + sub];   // L2-hot 64KB table
    const f32x4 g  = ln_g[sub];
    const f32x4 bb = ln_b[sub];
    const float A  = alpha[0];
    const float Bc = beta[0];

    f32x4 o;
    o.x = dx * r * g.x + bb.x + A * ye.x + Bc * qe.x;
    o.y = dy * r * g.y + bb.y + A * ye.y + Bc * qe.y;
    o.z = dz * r * g.z + bb.z + A * ye.z + Bc * qe.z;
    o.w = dw * r * g.w + bb.w + A * ye.w + Bc * qe.w;

    __builtin_nontemporal_store(o, &out[i]);  // streaming 268MB, keep L2 for tables
}

extern "C" void kernel_launch(void* const* d_in, const int* in_sizes, int n_in,
                              void* d_out, int out_size, void* d_ws, size_t ws_size,
                              hipStream_t stream) {
    const int*   year     = (const int*)d_in[0];
    const int*   answer   = (const int*)d_in[1];
    const f32x4* ans_emb  = (const f32x4*)d_in[2];
    const f32x4* lin_w    = (const f32x4*)d_in[3];
    const f32x4* lin_b    = (const f32x4*)d_in[4];
    const f32x4* ln_g     = (const f32x4*)d_in[5];
    const f32x4* ln_b     = (const f32x4*)d_in[6];
    const f32x4* year_emb = (const f32x4*)d_in[7];
    const f32x4* q_emb    = (const f32x4*)d_in[8];
    const float* alpha    = (const float*)d_in[9];
    const float* beta     = (const float*)d_in[10];
    float*       out      = (float*)d_out;

    const int B     = in_sizes[0];
    const int nrows = in_sizes[1];       // B*Q
    const int Q     = nrows / B;
    const int total = nrows * 4;         // one float4 per thread

    const int blocks = (total + 255) / 256;   // 65536 at full size — pure TLP

    const bool pow2 = (Q & (Q - 1)) == 0;
    int qShift = 0;
    while ((1 << qShift) < Q) ++qShift;

    if (pow2) {
        survey_fwd<true><<<blocks, 256, 0, stream>>>(
            year, answer, ans_emb, lin_w, lin_b, ln_g, ln_b, year_emb, q_emb,
            alpha, beta, (f32x4*)out, total, Q, qShift);
    } else {
        survey_fwd<false><<<blocks, 256, 0, stream>>>(
            year, answer, ans_emb, lin_w, lin_b, ln_g, ln_b, year_emb, q_emb,
            alpha, beta, (f32x4*)out, total, Q, qShift);
    }
}

// Round 4
// 50.774 us; speedup vs baseline: 1.9976x; 1.1393x over previous
//
#include <hip/hip_runtime.h>

// SurveyEmbeddings forward:
//   placeholder = (answer<=1) ? answer*lin_w + lin_b : ans_emb[answer]
//   out = LN(placeholder)*ln_g + ln_b + alpha*year_emb[year[b]] + beta*q_emb[q]
//
// out[B=4096, Q=1024, D=16] fp32 (268 MB) — memory-bound, write-dominated.
//
// R2 post-mortem: 2x unroll blew VGPRs -> occupancy halved -> 2x slower.
// R3 post-mortem: dropping the grid-stride loop un-hoisted the constant
//   loads (9 VMEM / 16B output) and added block churn -> 10% slower than R1.
// R4: R1's winning shape (grid-stride, hoisted constants) + launch_bounds
//   (256,8) to pin 8 waves/SIMD + int32 indexing + rare-branch lin_w/lin_b
//   + scalarized year lookup (block-uniform when Q % 64 == 0).

typedef float f32x4 __attribute__((ext_vector_type(4)));

#define LN_EPS 1e-5f

template <bool QPOW2>
__global__ __launch_bounds__(256, 8) void survey_fwd(
    const int* __restrict__ year,
    const int* __restrict__ answer,
    const f32x4* __restrict__ ans_emb,   // [VOCAB][4]
    const f32x4* __restrict__ lin_w,     // [4]
    const f32x4* __restrict__ lin_b,     // [4]
    const f32x4* __restrict__ ln_g,      // [4]
    const f32x4* __restrict__ ln_b,      // [4]
    const f32x4* __restrict__ year_emb,  // [N_YEARS][4]
    const f32x4* __restrict__ q_emb,     // [Q][4]
    const float* __restrict__ alpha,
    const float* __restrict__ beta,
    f32x4* __restrict__ out,             // [B*Q][4]
    int total, int Q, int qShift)
{
    const float A  = alpha[0];
    const float Bc = beta[0];

    const int sub = threadIdx.x & 3;     // float4 slot within the D=16 row
    const f32x4 g  = ln_g[sub];
    const f32x4 bb = ln_b[sub];

    const int stride = (int)(gridDim.x * blockDim.x);
    int i = (int)(blockIdx.x * blockDim.x + threadIdx.x);

    for (; i < total; i += stride) {
        const int row = i >> 2;
        const int a   = answer[row];       // 4 lanes broadcast-read same addr

        // categorical branch: gather 16B of the 64B embedding row (L2-hot)
        f32x4 v = ans_emb[a * 4 + sub];

        // continuous branch — rare (~0.05%); table loads stay inside so
        // lin_w/lin_b don't occupy hot-path VGPRs
        if (a <= 1) {
            const f32x4 w  = lin_w[sub];
            const f32x4 lb = lin_b[sub];
            const float af = (float)a;
            v.x = af * w.x + lb.x;
            v.y = af * w.y + lb.y;
            v.z = af * w.z + lb.z;
            v.w = af * w.w + lb.w;
        }

        // LayerNorm over D=16 across the 4-lane group
        float s = v.x + v.y + v.z + v.w;
        s += __shfl_xor(s, 1);
        s += __shfl_xor(s, 2);
        const float mu = s * 0.0625f;

        const float dx = v.x - mu, dy = v.y - mu, dz = v.z - mu, dw = v.w - mu;
        float ss = dx * dx + dy * dy + dz * dz + dw * dw;
        ss += __shfl_xor(ss, 1);
        ss += __shfl_xor(ss, 2);
        const float r = rsqrtf(ss * 0.0625f + LN_EPS);

        const int b = QPOW2 ? (row >> qShift) : (row / Q);
        const int q = QPOW2 ? (row & (Q - 1)) : (row - b * Q);

        // year index is uniform across the block when Q % 64 == 0
        // (a 256-thread block covers 64 consecutive rows, 64 | Q):
        // readfirstlane -> scalar load path, one less VMEM per iteration.
        int yr;
        if (QPOW2 && qShift >= 6) {
            const int b_u = __builtin_amdgcn_readfirstlane(b);
            yr = year[b_u];
        } else {
            yr = year[b];
        }
        const f32x4 ye = year_emb[yr * 4 + sub];
        const f32x4 qe = q_emb[q * 4 + sub];   // L2-hot 64KB table

        f32x4 o;
        o.x = dx * r * g.x + bb.x + A * ye.x + Bc * qe.x;
        o.y = dy * r * g.y + bb.y + A * ye.y + Bc * qe.y;
        o.z = dz * r * g.z + bb.z + A * ye.z + Bc * qe.z;
        o.w = dw * r * g.w + bb.w + A * ye.w + Bc * qe.w;

        __builtin_nontemporal_store(o, &out[i]);  // stream 268MB, keep L2 for tables
    }
}

extern "C" void kernel_launch(void* const* d_in, const int* in_sizes, int n_in,
                              void* d_out, int out_size, void* d_ws, size_t ws_size,
                              hipStream_t stream) {
    const int*   year     = (const int*)d_in[0];
    const int*   answer   = (const int*)d_in[1];
    const f32x4* ans_emb  = (const f32x4*)d_in[2];
    const f32x4* lin_w    = (const f32x4*)d_in[3];
    const f32x4* lin_b    = (const f32x4*)d_in[4];
    const f32x4* ln_g     = (const f32x4*)d_in[5];
    const f32x4* ln_b     = (const f32x4*)d_in[6];
    const f32x4* year_emb = (const f32x4*)d_in[7];
    const f32x4* q_emb    = (const f32x4*)d_in[8];
    const float* alpha    = (const float*)d_in[9];
    const float* beta     = (const float*)d_in[10];
    float*       out      = (float*)d_out;

    const int B     = in_sizes[0];
    const int nrows = in_sizes[1];       // B*Q
    const int Q     = nrows / B;
    const int total = nrows * 4;         // one float4 per lane-task

    const long long total_threads = (long long)total;
    int blocks = (int)((total_threads + 255) / 256);
    if (blocks > 8192) blocks = 8192;    // grid-stride: 8 iters/thread at full size

    const bool pow2 = (Q & (Q - 1)) == 0;
    int qShift = 0;
    while ((1 << qShift) < Q) ++qShift;

    if (pow2) {
        survey_fwd<true><<<blocks, 256, 0, stream>>>(
            year, answer, ans_emb, lin_w, lin_b, ln_g, ln_b, year_emb, q_emb,
            alpha, beta, (f32x4*)out, total, Q, qShift);
    } else {
        survey_fwd<false><<<blocks, 256, 0, stream>>>(
            year, answer, ans_emb, lin_w, lin_b, ln_g, ln_b, year_emb, q_emb,
            alpha, beta, (f32x4*)out, total, Q, qShift);
    }
}